// Round 1
// 108.013 us; speedup vs baseline: 1.1778x; 1.1778x over previous
//
#include <hip/hip_runtime.h>
#include <stdint.h>

// IDXST(4096x4096): y[r][k] = sum_n x[r][n] sin(pi*n*(2k+1)/8192).
// R6: same two-level mirror-fold decomposition as R5 — three GEMMs
// (U: 4096x2048x2048 via Bo, P,Q: 4096x1024x1024 via Bp/Bq) in ONE dispatch,
// plus prep + combine. NEW: the GEMM is ported from the 128x128 2-barrier
// structure (556 TF) to the 256x256 8-phase schedule (T3+T4+T2+T5):
//   - 8 waves (2Mx4N), per-wave 128x64 output, BK=64, acc = f32x4[8][4].
//   - LDS 128 KiB: 2 buffers x {A,B} x 2 halves (128x64 bf16 each).
//   - 1 half-tile staged per phase via global_load_lds(16B), linear LDS dest,
//     chunk^(row&7) involution applied to the GLOBAL source; ds_reads apply
//     the same XOR -> 0 bank conflicts (same swizzle R5 verified).
//   - counted s_waitcnt vmcnt(4) ONLY at phases 4/8. Steady-state issue order
//     per iteration (tiles t->buf0 p1-4, t+1->buf1 p5-8):
//       p1:Ah0[t+1] p2:Ah1[t+1] p3:Bh0[t+2] p4:Bh1[t+2]
//       p5:Ah0[t+2] p6:Ah1[t+2] p7:Bh0[t+3] p8:Bh1[t+3]
//     At p4 the per-wave queue is [Bh0,Bh1,Ah0,Ah1](t+1)+[Bh0,Bh1](t+2) = 12
//     loads; vmcnt(4) completes exactly tile t+1 and leaves 2 half-tiles in
//     flight. Symmetric at p8 for tile t+2. Buffer-overwrite safety: every
//     stage is issued after the trailing barrier of the last phase that reads
//     that LDS region (B halves free after p2/p6, A halves after p3/p7).
//   - setprio(1) around each 16-MFMA quadrant; peeled last iteration drains
//     with vmcnt(0).
// Grid: 256 blocks = 1/CU (bx<128: U, <192: P, else Q).
// ws (44 MB): xo 16 | xee 8 | xeo 8 | Bo 8 | Bp 2 | Bq 2.

#define NN 4096

typedef __attribute__((ext_vector_type(8))) short short8;
typedef __attribute__((ext_vector_type(4))) float f32x4;

__device__ __forceinline__ unsigned short f2bf(float f) {
  unsigned int u = __float_as_uint(f);
  u += 0x7fffu + ((u >> 16) & 1u);
  return (unsigned short)(u >> 16);
}

__device__ __forceinline__ void async_load16(const void* g, void* lds) {
  __builtin_amdgcn_global_load_lds(
      (const __attribute__((address_space(1))) unsigned int*)g,
      (__attribute__((address_space(3))) unsigned int*)lds, 16, 0, 0);
}

#define NXS (NN * NN / 8)        // 2M x-split threads (8 floats each)
#define NBO (2048 * 2048 / 4)    // 1M Bo threads
#define NBP (1024 * 1024 / 4)    // 256K Bp threads (Bq same)

// prep: xo[r][m]=x[r][2m+1]; xee[r][t]=x[r][4t]; xeo[r][t]=x[r][4t+2];
// Bo[c][m]=sin(pi(2m+1)(2c+1)/8192); Bp[c][t]=sin(pi*t*(2c+1)/2048);
// Bq[c][t]=sin(pi(2t+1)(2c+1)/4096)
__global__ void prep_kernel(const float* __restrict__ x,
                            unsigned short* __restrict__ xo,
                            unsigned short* __restrict__ xee,
                            unsigned short* __restrict__ xeo,
                            unsigned short* __restrict__ Bo,
                            unsigned short* __restrict__ Bp,
                            unsigned short* __restrict__ Bq) {
  int gi = blockIdx.x * blockDim.x + threadIdx.x;
  if (gi < NXS) {
    int g = gi & 511;            // 8-float group in row
    int r = gi >> 9;
    const float4* src = (const float4*)(x + (size_t)r * NN + g * 8);
    float4 v0 = src[0], v1 = src[1];    // n = 8g+0..3, 8g+4..7
    ushort4 ov;                          // odd n -> m = 4g..4g+3
    ov.x = f2bf(v0.y); ov.y = f2bf(v0.w); ov.z = f2bf(v1.y); ov.w = f2bf(v1.w);
    *(ushort4*)&xo[(size_t)r * 2048 + g * 4] = ov;
    unsigned int ee = ((unsigned)f2bf(v1.x) << 16) | f2bf(v0.x);  // t=2g,2g+1
    *(unsigned int*)&xee[(size_t)r * 1024 + g * 2] = ee;
    unsigned int eo = ((unsigned)f2bf(v1.z) << 16) | f2bf(v0.z);
    *(unsigned int*)&xeo[(size_t)r * 1024 + g * 2] = eo;
  } else if (gi < NXS + NBO) {
    int i = gi - NXS;
    int m0 = (i & 511) * 4;
    int c = i >> 9;
    unsigned int tw = 2u * (unsigned)c + 1u;
    const float sc = 3.14159265358979323846f / 8192.0f;
    ushort4 o; unsigned int ph;
    ph = ((unsigned)(2 * (m0 + 0) + 1) * tw) & 16383u; o.x = f2bf(__sinf((float)ph * sc));
    ph = ((unsigned)(2 * (m0 + 1) + 1) * tw) & 16383u; o.y = f2bf(__sinf((float)ph * sc));
    ph = ((unsigned)(2 * (m0 + 2) + 1) * tw) & 16383u; o.z = f2bf(__sinf((float)ph * sc));
    ph = ((unsigned)(2 * (m0 + 3) + 1) * tw) & 16383u; o.w = f2bf(__sinf((float)ph * sc));
    *(ushort4*)&Bo[(size_t)c * 2048 + m0] = o;
  } else if (gi < NXS + NBO + NBP) {
    int i = gi - NXS - NBO;
    int t0 = (i & 255) * 4;
    int c = i >> 8;
    unsigned int tw = 2u * (unsigned)c + 1u;
    const float sc = 3.14159265358979323846f / 2048.0f;
    ushort4 o; unsigned int ph;
    ph = ((unsigned)(t0 + 0) * tw) & 4095u; o.x = f2bf(__sinf((float)ph * sc));
    ph = ((unsigned)(t0 + 1) * tw) & 4095u; o.y = f2bf(__sinf((float)ph * sc));
    ph = ((unsigned)(t0 + 2) * tw) & 4095u; o.z = f2bf(__sinf((float)ph * sc));
    ph = ((unsigned)(t0 + 3) * tw) & 4095u; o.w = f2bf(__sinf((float)ph * sc));
    *(ushort4*)&Bp[(size_t)c * 1024 + t0] = o;
  } else {
    int i = gi - NXS - NBO - NBP;
    int t0 = (i & 255) * 4;
    int c = i >> 8;
    unsigned int tw = 2u * (unsigned)c + 1u;
    const float sc = 3.14159265358979323846f / 4096.0f;
    ushort4 o; unsigned int ph;
    ph = ((unsigned)(2 * (t0 + 0) + 1) * tw) & 8191u; o.x = f2bf(__sinf((float)ph * sc));
    ph = ((unsigned)(2 * (t0 + 1) + 1) * tw) & 8191u; o.y = f2bf(__sinf((float)ph * sc));
    ph = ((unsigned)(2 * (t0 + 2) + 1) * tw) & 8191u; o.z = f2bf(__sinf((float)ph * sc));
    ph = ((unsigned)(2 * (t0 + 3) + 1) * tw) & 8191u; o.w = f2bf(__sinf((float)ph * sc));
    *(ushort4*)&Bq[(size_t)c * 1024 + t0] = o;
  }
}

// ---- 8-phase 256x256 GEMM machinery ------------------------------------
// LDS ushort offsets: region(buf b, mat m(0=A,1=B), half h) = (4b+2m+h)*8192.
#define PH_BAR  __builtin_amdgcn_s_barrier()
#define W_LGKM0 asm volatile("s_waitcnt lgkmcnt(0)" ::: "memory")
#define W_VM4   asm volatile("s_waitcnt vmcnt(4)" ::: "memory")
#define W_VM0   asm volatile("s_waitcnt vmcnt(0)" ::: "memory")
#define PRIO1   __builtin_amdgcn_s_setprio(1)
#define PRIO0   __builtin_amdgcn_s_setprio(0)

// Stage one 128x64 half-tile: rows prow0+half*128+[0,128), k cols [koff,koff+64).
// Linear LDS dest (tid*16B, +8KB for rows 64-127); source chunk pre-swizzled
// by the same chunk^(row&7) involution the ds_reads apply.
#define STAGE(Mat, prow0, koff, half, off) do {                                 \
    const unsigned short* _s =                                                  \
        (Mat) + (size_t)((prow0) + (half) * 128 + st_r) * K + (koff) + st_c;    \
    async_load16(_s, &lds[(off) + tid * 8]);                                    \
    async_load16(_s + (size_t)64 * K, &lds[(off) + 4096 + tid * 8]);            \
  } while (0)

// A-frags for quadrant row-half mh of buffer b (wave's half = wm): 8 reads.
#define LOADA(b, mh) do {                                                       \
    const int _ab = ((b) * 4 + wm) * 8192 + (mh) * 4096 + lr * 64;              \
    _Pragma("unroll") for (int _i = 0; _i < 4; ++_i) {                          \
      av[_i][0] = *(const short8*)&lds[_ab + _i * 1024 + cA0];                  \
      av[_i][1] = *(const short8*)&lds[_ab + _i * 1024 + cA1];                  \
    }                                                                           \
  } while (0)

// B-frags for quadrant col-half nh of buffer b (wave strip wn): 4 reads.
#define LOADB(b, nh, BV) do {                                                   \
    const int _bb = ((b) * 4 + 2 + wnh) * 8192 + wnl * 4096 + (nh) * 2048 +     \
                    lr * 64;                                                    \
    _Pragma("unroll") for (int _j = 0; _j < 2; ++_j) {                          \
      BV[_j][0] = *(const short8*)&lds[_bb + _j * 1024 + cA0];                  \
      BV[_j][1] = *(const short8*)&lds[_bb + _j * 1024 + cA1];                  \
    }                                                                           \
  } while (0)

// One C-quadrant x K=64: 16 MFMA.
#define MMAQ(mh, nh, BV) do {                                                   \
    _Pragma("unroll") for (int _k = 0; _k < 2; ++_k)                            \
    _Pragma("unroll") for (int _i = 0; _i < 4; ++_i)                            \
    _Pragma("unroll") for (int _j = 0; _j < 2; ++_j)                            \
      acc[(mh) * 4 + _i][(nh) * 2 + _j] =                                       \
          __builtin_amdgcn_mfma_f32_16x16x32_bf16(                              \
              av[_i][_k], BV[_j][_k], acc[(mh) * 4 + _i][(nh) * 2 + _j],        \
              0, 0, 0);                                                         \
  } while (0)

__global__ __launch_bounds__(512, 2) void gemm3_kernel(
    const unsigned short* __restrict__ xo,
    const unsigned short* __restrict__ xee,
    const unsigned short* __restrict__ xeo,
    const unsigned short* __restrict__ Bo,
    const unsigned short* __restrict__ Bp,
    const unsigned short* __restrict__ Bq,
    float* __restrict__ out) {
  __shared__ __align__(16) unsigned short lds[65536];   // 128 KiB

  const int bx = blockIdx.x;
  const unsigned short* A;
  const unsigned short* Bm;
  int K, row0, ncol0, col0;
  if (bx < 128) {
    A = xo;  Bm = Bo; K = 2048;
    row0 = (bx & 15) * 256; ncol0 = (bx >> 4) * 256; col0 = ncol0;
  } else if (bx < 192) {
    int b = bx - 128;
    A = xee; Bm = Bp; K = 1024;
    row0 = (b & 15) * 256; ncol0 = (b >> 4) * 256; col0 = 2048 + ncol0;
  } else {
    int b = bx - 192;
    A = xeo; Bm = Bq; K = 1024;
    row0 = (b & 15) * 256; ncol0 = (b >> 4) * 256; col0 = 3072 + ncol0;
  }
  const int NT = K >> 6;           // K-tiles of 64 (32 for U, 16 for P/Q)

  const int tid = threadIdx.x;
  const int lane = tid & 63;
  const int wave = tid >> 6;
  const int wm = wave >> 2;        // 0..1 : 128-row half of C
  const int wn = wave & 3;         // 0..3 : 64-col strip of C
  const int wnh = wn >> 1, wnl = wn & 1;
  const int lr = lane & 15, kq = lane >> 4;
  const int st_r = tid >> 3;                         // staging row 0..63
  const int st_c = ((tid & 7) ^ (st_r & 7)) * 8;     // pre-swizzled src chunk
  const int cA0 = (kq ^ (lr & 7)) * 8;               // swizzled ds_read chunks
  const int cA1 = ((4 + kq) ^ (lr & 7)) * 8;

  f32x4 acc[8][4];
#pragma unroll
  for (int i = 0; i < 8; ++i)
#pragma unroll
    for (int j = 0; j < 4; ++j)
      acc[i][j] = (f32x4){0.f, 0.f, 0.f, 0.f};
  short8 av[4][2], bv0[2][2], bv1[2][2];

  // Prologue: A0 full, B0 full, B1 full (12 loads); wait tile0 (vmcnt(4)
  // leaves B1's 4 loads in flight).
  STAGE(A,  row0,  0,  0, 0);
  STAGE(A,  row0,  0,  1, 8192);
  STAGE(Bm, ncol0, 0,  0, 16384);
  STAGE(Bm, ncol0, 0,  1, 24576);
  STAGE(Bm, ncol0, 64, 0, 49152);
  STAGE(Bm, ncol0, 64, 1, 57344);
  W_VM4; PH_BAR;

  const int NITER = NT >> 1;
  for (int it = 0; it < NITER - 1; ++it) {
    const int t64 = it << 7;       // k-offset of tile t = 2*it
    // ---- tile t (buf0) ----
    // p1: q(0,0); stage Ah0[t+1] -> buf1
    LOADA(0, 0); LOADB(0, 0, bv0);
    STAGE(A, row0, t64 + 64, 0, 32768);
    PH_BAR; W_LGKM0; PRIO1; MMAQ(0, 0, bv0); PRIO0; PH_BAR;
    // p2: q(0,1); stage Ah1[t+1]
    LOADB(0, 1, bv1);
    STAGE(A, row0, t64 + 64, 1, 40960);
    PH_BAR; W_LGKM0; PRIO1; MMAQ(0, 1, bv1); PRIO0; PH_BAR;
    // p3: q(1,1); stage Bh0[t+2] -> buf0 (B reads ended p2)
    LOADA(0, 1);
    STAGE(Bm, ncol0, t64 + 128, 0, 16384);
    PH_BAR; W_LGKM0; PRIO1; MMAQ(1, 1, bv1); PRIO0; PH_BAR;
    // p4: q(1,0); stage Bh1[t+2]; counted wait -> tile t+1 resident
    STAGE(Bm, ncol0, t64 + 128, 1, 24576);
    PH_BAR; PRIO1; MMAQ(1, 0, bv0); PRIO0; W_VM4; PH_BAR;
    // ---- tile t+1 (buf1) ----
    // p5: q(0,0); stage Ah0[t+2] -> buf0 (A reads ended p3)
    LOADA(1, 0); LOADB(1, 0, bv0);
    STAGE(A, row0, t64 + 128, 0, 0);
    PH_BAR; W_LGKM0; PRIO1; MMAQ(0, 0, bv0); PRIO0; PH_BAR;
    // p6: q(0,1); stage Ah1[t+2]
    LOADB(1, 1, bv1);
    STAGE(A, row0, t64 + 128, 1, 8192);
    PH_BAR; W_LGKM0; PRIO1; MMAQ(0, 1, bv1); PRIO0; PH_BAR;
    // p7: q(1,1); stage Bh0[t+3] -> buf1 (B reads ended p6)
    LOADA(1, 1);
    STAGE(Bm, ncol0, t64 + 192, 0, 49152);
    PH_BAR; W_LGKM0; PRIO1; MMAQ(1, 1, bv1); PRIO0; PH_BAR;
    // p8: q(1,0); stage Bh1[t+3]; counted wait -> tile t+2 resident
    STAGE(Bm, ncol0, t64 + 192, 1, 57344);
    PH_BAR; PRIO1; MMAQ(1, 0, bv0); PRIO0; W_VM4; PH_BAR;
  }

  // Peeled last iteration (tiles NT-2 -> buf0, NT-1 -> buf1): only A[NT-1]
  // left to stage; drain to vmcnt(0) at p4.
  {
    const int t64 = (NT - 2) << 6;
    LOADA(0, 0); LOADB(0, 0, bv0);
    STAGE(A, row0, t64 + 64, 0, 32768);
    PH_BAR; W_LGKM0; PRIO1; MMAQ(0, 0, bv0); PRIO0; PH_BAR;
    LOADB(0, 1, bv1);
    STAGE(A, row0, t64 + 64, 1, 40960);
    PH_BAR; W_LGKM0; PRIO1; MMAQ(0, 1, bv1); PRIO0; PH_BAR;
    LOADA(0, 1);
    PH_BAR; W_LGKM0; PRIO1; MMAQ(1, 1, bv1); PRIO0; PH_BAR;
    PRIO1; MMAQ(1, 0, bv0); PRIO0; W_VM0; PH_BAR;
    // tile NT-1 (buf1): no more staging, no barriers needed
    LOADA(1, 0); LOADB(1, 0, bv0);
    W_LGKM0; PRIO1; MMAQ(0, 0, bv0); PRIO0;
    LOADB(1, 1, bv1);
    W_LGKM0; PRIO1; MMAQ(0, 1, bv1); PRIO0;
    LOADA(1, 1);
    W_LGKM0; PRIO1; MMAQ(1, 1, bv1); MMAQ(1, 0, bv0); PRIO0;
  }

  // C/D layout: col=lane&15, row=quad*4+reg
#pragma unroll
  for (int i = 0; i < 8; ++i)
#pragma unroll
    for (int j = 0; j < 4; ++j)
#pragma unroll
      for (int r = 0; r < 4; ++r) {
        int row = row0 + wm * 128 + i * 16 + kq * 4 + r;
        int col = col0 + wn * 64 + j * 16 + lr;
        out[(size_t)row * NN + col] = acc[i][j][r];
      }
}

// In-place combine, both fold levels. Row layout on entry:
// [0:2048)=u, [2048:3072)=p, [3072:4096)=q.
// v[k']=p+q, v[2047-k']=q-p (k'<1024); y[k]=v[k]+u[k], y[4095-k]=u[k]-v[k].
__global__ void combine_kernel(float* __restrict__ out) {
  int t = blockIdx.x * blockDim.x + threadIdx.x;   // 4096 rows * 128 threads
  int r = t >> 7;
  int k0 = (t & 127) * 4;                          // [0,512)
  float* row = out + (size_t)r * NN;
  float U0[4], U1[4], U2[4], U3[4], P0[4], P1[4], Q0[4], Q1[4];
  *(float4*)U0 = *(float4*)&row[k0];          // u[k0+e]
  *(float4*)U1 = *(float4*)&row[1020 - k0];   // u[1023-k'] rev
  *(float4*)U2 = *(float4*)&row[1024 + k0];   // u[1024+k0+e]
  *(float4*)U3 = *(float4*)&row[2044 - k0];   // u[2047-k'] rev
  *(float4*)P0 = *(float4*)&row[2048 + k0];   // p[k0+e]
  *(float4*)P1 = *(float4*)&row[3068 - k0];   // p[1023-k'] rev
  *(float4*)Q0 = *(float4*)&row[3072 + k0];   // q[k0+e]
  *(float4*)Q1 = *(float4*)&row[4092 - k0];   // q[1023-k'] rev
  float YA[4], YB[4], YC[4], YD[4], YE[4], YF[4], YG[4], YH[4];
#pragma unroll
  for (int e = 0; e < 4; ++e) {
    float v1 = P0[e] + Q0[e];        // v[k']
    float v2 = Q0[e] - P0[e];        // v[2047-k']
    float um = U3[3 - e];            // u[2047-k']
    YA[e] = v1 + U0[e];              // y[k']
    YB[3 - e] = U0[e] - v1;          // y[4095-k']
    YC[3 - e] = v2 + um;             // y[2047-k']
    YD[e] = um - v2;                 // y[2048+k']
    float pm = P1[3 - e], qm = Q1[3 - e];
    float w1 = pm + qm;              // v[1023-k']
    float w2 = qm - pm;              // v[1024+k']
    float umm = U1[3 - e];           // u[1023-k']
    YE[3 - e] = w1 + umm;            // y[1023-k']
    YF[e] = umm - w1;                // y[3072+k']
    YG[e] = w2 + U2[e];              // y[1024+k']
    YH[3 - e] = U2[e] - w2;          // y[3071-k']
  }
  *(float4*)&row[k0] = *(float4*)YA;
  *(float4*)&row[4092 - k0] = *(float4*)YB;
  *(float4*)&row[2044 - k0] = *(float4*)YC;
  *(float4*)&row[2048 + k0] = *(float4*)YD;
  *(float4*)&row[1020 - k0] = *(float4*)YE;
  *(float4*)&row[3072 + k0] = *(float4*)YF;
  *(float4*)&row[1024 + k0] = *(float4*)YG;
  *(float4*)&row[3068 - k0] = *(float4*)YH;
}

extern "C" void kernel_launch(void* const* d_in, const int* in_sizes, int n_in,
                              void* d_out, int out_size, void* d_ws, size_t ws_size,
                              hipStream_t stream) {
  const float* x = (const float*)d_in[0];
  float* out = (float*)d_out;
  unsigned short* xo  = (unsigned short*)d_ws;            // 16 MB
  unsigned short* xee = xo + (size_t)NN * 2048;           // 8 MB
  unsigned short* xeo = xee + (size_t)NN * 1024;          // 8 MB
  unsigned short* Bo  = xeo + (size_t)NN * 1024;          // 8 MB
  unsigned short* Bp  = Bo + (size_t)2048 * 2048;         // 2 MB
  unsigned short* Bq  = Bp + (size_t)1024 * 1024;         // 2 MB -> 44 MB total

  int prep_threads = NXS + NBO + 2 * NBP;
  prep_kernel<<<prep_threads / 256, 256, 0, stream>>>(x, xo, xee, xeo, Bo, Bp, Bq);

  gemm3_kernel<<<256, 512, 0, stream>>>(xo, xee, xeo, Bo, Bp, Bq, out);

  combine_kernel<<<NN * 128 / 256, 256, 0, stream>>>(out);
}